// Round 5
// baseline (402.814 us; speedup 1.0000x reference)
//
#include <hip/hip_runtime.h>
#include <stdint.h>

// W8A8B32O32 Linear: y[m][n] = sum_k x[m][k]*w[n][k] + bias[n]
// M=8192, N=4096, K=4096. Inputs arrive as int32 (one int per logical int8
// element); pack to int8 in d_ws, then run the i8 MFMA GEMM.
#define M_TOT 8192
#define N_TOT 4096
#define K_TOT 4096

typedef int v4i  __attribute__((ext_vector_type(4)));
typedef int v16i __attribute__((ext_vector_type(16)));

__device__ __forceinline__ void gload_lds16(const void* g, void* l) {
    __builtin_amdgcn_global_load_lds(
        (const __attribute__((address_space(1))) unsigned int*)g,
        (__attribute__((address_space(3))) unsigned int*)l,
        16, 0, 0);
}

// gfx9 s_waitcnt simm16: vmcnt[3:0]@[3:0], expcnt@[6:4], lgkmcnt@[11:8],
// vmcnt[5:4]@[15:14].
#define WAIT_V2_L0() __builtin_amdgcn_s_waitcnt(0x0072)  // vmcnt(2) lgkmcnt(0)
#define WAIT_V0_L0() __builtin_amdgcn_s_waitcnt(0x0070)  // vmcnt(0) lgkmcnt(0)
#define WAIT_V4()    __builtin_amdgcn_s_waitcnt(0x0f74)  // vmcnt(4), lgkm free
#define SBAR()       __builtin_amdgcn_s_barrier()
#define SFENCE()     __builtin_amdgcn_sched_barrier(0)

// ---- fused pack int32 -> int8: 64B loads -> 16B store per thread-iter ----
// BW-bound at 240 MB (~45 us); both this and the split variant measure the
// same -> already at the traffic floor.
__global__ __launch_bounds__(256) void pack2(
        const int4* __restrict__ xs, int4* __restrict__ xd,
        const int4* __restrict__ ws, int4* __restrict__ wd) {
    const int t = blockIdx.x * 256 + threadIdx.x;       // 0..524287
#pragma unroll
    for (int it = 0; it < 6; ++it) {
        const long g = (long)it * 524288 + t;
        const int4* __restrict__ src = (it < 4) ? xs : ws;
        int4* __restrict__ dst       = (it < 4) ? xd : wd;
        const long o = (it < 4) ? g : g - 2097152;
        int4 r;
        int* rp = (int*)&r;
#pragma unroll
        for (int q = 0; q < 4; ++q) {
            const int4 a = src[o * 4 + q];
            rp[q] = (a.x & 255) | ((a.y & 255) << 8) |
                    ((a.z & 255) << 16) | (a.w << 24);
        }
        dst[o] = r;
    }
}

// ---- GEMM: 512 threads = 8 waves (2/SIMD) computing a 256x256 tile -------
// R4 post-mortem: per-SIMD-iter wall 2680 cyc = MFMA 1170 + LDS pipe ~1380
// (reads 96KB + DMA writes 32KB + 384 conflict cyc, CU-shared) -- nearly
// ADDITIVE. Single-barrier cadence lets both waves/SIMD collide their read
// bursts with MFMA clusters. Fix: m201 double-barrier phase discipline --
// [read burst issue | DMA] BAR [MFMA cluster] (waits) BAR -- so all 8
// waves' ds_reads drain in the LDS pipe DURING the MFMA clusters, in strict
// global alternation (measured 62% MfmaUtil on this geometry for bf16).
//
// Per K-iter (tile kt in A0/B0, kt+1 in A1/B1, kt+2 -> A2/B2):
//  ph0: 6 ds_read (kt, kk=1 -> a1/b1); 2 DMA A(kt+2)
//       BAR(1); setprio1; 8 MFMA kk=0 (a0/b0); setprio0
//       vmcnt(2) lgkmcnt(0)   [kt+1 landed (mine); my reads retired]
//       BAR(2)                [publish: kt+1 readable everywhere]
//  ph1: 6 ds_read (kt+1, kk=0 -> a0/b0); 2 DMA B(kt+2)
//       BAR(3); setprio1; 8 MFMA kk=1 (a1/b1); setprio0
//       BAR(4)
//  rotate buffers.
// vmcnt ledger at ph0 wait: outstanding = A(kt+1)2 + B(kt+1)2 + A(kt+2)2
// = 6 -> vmcnt(2) == tiles kt+1 fully landed (in-order decrement). Tail
// iters use vmcnt(0). Buffer-reuse proof: DMAs into buffer X (tile kt+2,
// issued iter kt) follow iter kt-1's lgkmcnt(0)+BAR(2), which retires every
// wave's last reads of X (tile kt-1, read iter kt-1 ph0). Reads of kt+1 at
// ph1 follow each wave's own vmcnt drain + BAR(2). Explicit waits are
// REQUIRED: compiler alias analysis does not connect global_load_lds's LDS
// write to the ds_reads.
// XOR chunk swizzle: stored_chunk = logical_chunk ^ ((row>>1)&3); staging
// stays linear-in-load-order (global_load_lds needs wave-uniform LDS base).
__global__ __launch_bounds__(512, 2) void i8gemm_bias(
        const signed char* __restrict__ x,
        const signed char* __restrict__ w,
        const int* __restrict__ bias,
        int* __restrict__ out) {
    __shared__ __align__(16) signed char la[3][256 * 64];
    __shared__ __align__(16) signed char lb[3][256 * 64];

    const int tid  = threadIdx.x;
    const int lane = tid & 63;           // 0..63
    const int wv   = tid >> 6;           // wave 0..7
    const int l31  = lane & 31;
    const int kh   = lane >> 5;          // K-half this lane supplies to MFMA
    const int wr   = wv >> 2;            // quadrant row (0..1) -> 128 rows
    const int wc   = wv & 3;             // quadrant col (0..3) -> 64 cols

    // XCD-aware bijective swizzle (512 blocks, 512%8==0): XCD k gets a
    // contiguous swz-range -> 4 A-panels x all 16 B-panels per XCD.
    const int flat = blockIdx.y * gridDim.x + blockIdx.x;   // 0..511
    const int swz  = (flat & 7) * 64 + (flat >> 3);
    const int bn0  = (swz & 15) * 256;
    const int bm0  = (swz >> 4) * 256;

    // Fused bias: C/D col = lane&31 -> bias is lane-constant per fragment.
    int bv[2];
#pragma unroll
    for (int j = 0; j < 2; ++j) bv[j] = bias[bn0 + wc * 64 + j * 32 + l31];
    v16i acc[4][2];
#pragma unroll
    for (int i = 0; i < 4; ++i)
#pragma unroll
        for (int j = 0; j < 2; ++j)
#pragma unroll
            for (int r = 0; r < 16; ++r) acc[i][j][r] = bv[j];

    // Staging: wave wv covers rows [wv*32, wv*32+32) of both A and B tiles:
    // 2 issues x (64 lanes x 16 B) each. Issue i covers rows i*16+(lane>>2);
    // stored chunk = lane&3; fetched chunk = (lane&3) ^ ((row>>1)&3)
    // = (lane&3) ^ ((lane>>3)&3).
    const int fc = (lane & 3) ^ ((lane >> 3) & 3);
    const signed char* pa = x + (long)(bm0 + wv * 32 + (lane >> 2)) * K_TOT + fc * 16;
    const signed char* pb = w + (long)(bn0 + wv * 32 + (lane >> 2)) * K_TOT + fc * 16;
    const int lbase = wv * 32 * 64;      // byte offset of this wave's rows

    // Fragment reads: A row = wr*128 + i*32 + l31, B row = wc*64 + j*32 + l31
    // -> swizzle = (l31>>1)&3 (bases are 0 mod 8). Logical chunk kk*2+kh is
    // stored at position (kk*2+kh)^swr.
    const int swr  = (l31 >> 1) & 3;
    const int aoff = (wr * 128 + l31) * 64;
    const int boff = (wc * 64  + l31) * 64;
    const int cs0  = ((kh    ) ^ swr) * 16;   // kk=0 chunk byte offset
    const int cs1  = ((2 + kh) ^ swr) * 16;   // kk=1 chunk byte offset

    // Rotating buffer pointers: A0/B0 = tile kt, A1/B1 = kt+1, A2/B2 = kt+2.
    signed char* A0 = &la[0][0]; signed char* A1 = &la[1][0]; signed char* A2 = &la[2][0];
    signed char* B0 = &lb[0][0]; signed char* B1 = &lb[1][0]; signed char* B2 = &lb[2][0];

    // Prologue: stage tile 0 then tile 1 (grouped per tile: vmcnt decrements
    // in issue order). 4 DMAs per tile per wave (2 A-rows + 2 B-rows).
#pragma unroll
    for (int i = 0; i < 2; ++i) {
        gload_lds16(pa + (long)i * 16 * K_TOT, A0 + lbase + i * 1024);
        gload_lds16(pb + (long)i * 16 * K_TOT, B0 + lbase + i * 1024);
    }
#pragma unroll
    for (int i = 0; i < 2; ++i) {
        gload_lds16(pa + 64 + (long)i * 16 * K_TOT, A1 + lbase + i * 1024);
        gload_lds16(pb + 64 + (long)i * 16 * K_TOT, B1 + lbase + i * 1024);
    }
    WAIT_V4();                 // tile 0 landed (tile 1's 4 stay in flight)
    SBAR();
    SFENCE();

    // Preload kk=0 fragments of tile 0.
    v4i a0[4], b0[2], a1[4], b1[2];
#pragma unroll
    for (int i = 0; i < 4; ++i) a0[i] = *(const v4i*)(A0 + aoff + i * 2048 + cs0);
#pragma unroll
    for (int j = 0; j < 2; ++j) b0[j] = *(const v4i*)(B0 + boff + j * 2048 + cs0);

    const int NT = K_TOT / 64;           // 64 K-tiles
    for (int kt = 0; kt < NT; ++kt) {
        SFENCE();
        // ph0-a) ds_read kk=1 of tile kt (consumed by ph1's MFMA).
#pragma unroll
        for (int i = 0; i < 4; ++i) a1[i] = *(const v4i*)(A0 + aoff + i * 2048 + cs1);
#pragma unroll
        for (int j = 0; j < 2; ++j) b1[j] = *(const v4i*)(B0 + boff + j * 2048 + cs1);
        SFENCE();
        // ph0-b) Issue A-half prefetch of tile kt+2 (fire-and-forget).
        if (kt + 2 < NT) {
            const long k0 = (long)(kt + 2) * 64;
#pragma unroll
            for (int i = 0; i < 2; ++i)
                gload_lds16(pa + k0 + (long)i * 16 * K_TOT, A2 + lbase + i * 1024);
        }
        SFENCE();
        SBAR();                // (1) burst-align: reads drain under MFMAs
        __builtin_amdgcn_s_setprio(1);
#pragma unroll
        for (int i = 0; i < 4; ++i)
#pragma unroll
            for (int j = 0; j < 2; ++j)
                acc[i][j] = __builtin_amdgcn_mfma_i32_32x32x32_i8(
                    a0[i], b0[j], acc[i][j], 0, 0, 0);
        __builtin_amdgcn_s_setprio(0);
        SFENCE();
        // publish wait: tile kt+1 landed (mine); my buffer reads retired.
        if (kt + 2 < NT) { WAIT_V2_L0(); } else { WAIT_V0_L0(); }
        SFENCE();
        SBAR();                // (2) publish barrier
        SFENCE();
        // ph1-a) ds_read kk=0 of tile kt+1.
        if (kt + 1 < NT) {
#pragma unroll
            for (int i = 0; i < 4; ++i) a0[i] = *(const v4i*)(A1 + aoff + i * 2048 + cs0);
#pragma unroll
            for (int j = 0; j < 2; ++j) b0[j] = *(const v4i*)(B1 + boff + j * 2048 + cs0);
        }
        SFENCE();
        // ph1-b) Issue B-half prefetch of tile kt+2 (fire-and-forget).
        if (kt + 2 < NT) {
            const long k0 = (long)(kt + 2) * 64;
#pragma unroll
            for (int i = 0; i < 2; ++i)
                gload_lds16(pb + k0 + (long)i * 16 * K_TOT, B2 + lbase + i * 1024);
        }
        SFENCE();
        SBAR();                // (3) burst-align
        __builtin_amdgcn_s_setprio(1);
#pragma unroll
        for (int i = 0; i < 4; ++i)
#pragma unroll
            for (int j = 0; j < 2; ++j)
                acc[i][j] = __builtin_amdgcn_mfma_i32_32x32x32_i8(
                    a1[i], b1[j], acc[i][j], 0, 0, 0);
        __builtin_amdgcn_s_setprio(0);
        SFENCE();
        SBAR();                // (4) keep waves phase-locked into next iter
        SFENCE();

        // Rotate buffers (register pointer swap, no dynamic indexing).
        signed char* t;
        t = A0; A0 = A1; A1 = A2; A2 = t;
        t = B0; B0 = B1; B1 = B2; B2 = t;
    }

    // Epilogue: C/D layout col=lane&31, row=(reg&3)+8*(reg>>2)+4*(lane>>5).
#pragma unroll
    for (int i = 0; i < 4; ++i) {
        const int mbase = bm0 + wr * 128 + i * 32 + 4 * kh;
#pragma unroll
        for (int j = 0; j < 2; ++j) {
            const int n = bn0 + wc * 64 + j * 32 + l31;
#pragma unroll
            for (int r = 0; r < 16; ++r) {
                const int m = mbase + (r & 3) + 8 * (r >> 2);
                out[(long)m * N_TOT + n] = acc[i][j][r];
            }
        }
    }
}

extern "C" void kernel_launch(void* const* d_in, const int* in_sizes, int n_in,
                              void* d_out, int out_size, void* d_ws, size_t ws_size,
                              hipStream_t stream) {
    const int* x32  = (const int*)d_in[0];  // [8192,4096] logical i8 as i32
    const int* w32  = (const int*)d_in[1];  // [4096,4096] logical i8 as i32
    const int* bias = (const int*)d_in[2];  // [4096] i32
    int*       out  = (int*)d_out;          // [8192,4096] i32

    signed char* xp = (signed char*)d_ws;
    signed char* wp = (signed char*)d_ws + (size_t)M_TOT * K_TOT;

    pack2<<<2048, 256, 0, stream>>>((const int4*)x32, (int4*)xp,
                                    (const int4*)w32, (int4*)wp);

    dim3 grid(N_TOT / 256, M_TOT / 256);  // (16, 32)
    i8gemm_bias<<<grid, 512, 0, stream>>>(xp, wp, bias, out);
}